// Round 11
// baseline (745.783 us; speedup 1.0000x reference)
//
#include <hip/hip_runtime.h>
#include <math.h>

#define NN 3072
#define NH 8
#define FO 64
#define FCAT 512
#define MAXDEG 128
#define ALPHA 0.2f
#define NBLK 512   // 2 blocks/CU * 256 CU — co-residency guaranteed (80KB/CU LDS, launch_bounds(256,2))

typedef __attribute__((ext_vector_type(8))) short bf16x8;
typedef __attribute__((ext_vector_type(4))) float f32x4;

static __device__ __forceinline__ unsigned short f2bf(float v) {
    union { float f; unsigned u; } x; x.f = v;
    unsigned r = x.u + 0x7fffu + ((x.u >> 16) & 1u);
    return (unsigned short)(r >> 16);
}
static __device__ __forceinline__ float bf2f(unsigned short b) {
    union { unsigned u; float f; } x; x.u = ((unsigned)b) << 16;
    return x.f;
}

// software grid barrier: monotone counter, release-add / spin / acquire
static __device__ __forceinline__ void gridbar(unsigned* bar, unsigned target) {
    __syncthreads();
    if (threadIdx.x == 0) {
        __threadfence();
        atomicAdd(bar, 1u);
        while (__hip_atomic_load(bar, __ATOMIC_RELAXED, __HIP_MEMORY_SCOPE_AGENT) < target) {
            __builtin_amdgcn_s_sleep(2);
        }
        __threadfence();
    }
    __syncthreads();
}

// Persistent kernel: prelude + 4 x (gemm_ee, attn_agg) with software grid barriers.
__global__ __launch_bounds__(256, 2) void gat_all_k(
    const float* __restrict__ x, const float* __restrict__ adj,
    const float* __restrict__ W1, const float* __restrict__ W2,
    const float* __restrict__ W3, const float* __restrict__ W4,
    const float* __restrict__ a1, const float* __restrict__ a2,
    const float* __restrict__ a3, const float* __restrict__ a4,
    unsigned short* __restrict__ Ah, unsigned short* __restrict__ Al,
    unsigned short* __restrict__ Wth, unsigned short* __restrict__ Wtl,
    int* __restrict__ deg, int* __restrict__ nbr,
    float* __restrict__ WhF, float* __restrict__ esrc, float* __restrict__ edst,
    float* __restrict__ out, unsigned* bar)
{
    __shared__ __align__(16) unsigned char smem[40960];

    const int b = blockIdx.x;
    const int tid = threadIdx.x;
    const int lane = tid & 63;
    const int ws = tid >> 6;
    unsigned ph = 0;

    // ================= phase 0: prelude =================
    for (int t = b; t < 1232; t += NBLK) {
        if (t < 256) {
            int base = t * 1536 + tid;
            #pragma unroll
            for (int i = 0; i < 6; ++i) {
                int idx = base + i * 256;
                float v = x[idx];
                unsigned short hb = f2bf(v);
                Ah[idx] = hb;
                Al[idx] = f2bf(v - bf2f(hb));
            }
        } else if (t < 464) {
            int tw = t - 256;
            float (*tt)[65] = (float(*)[65])smem;
            const float* W; int K; int local; size_t obase;
            if (tw < 16)       { W = W1; K = 128; local = tw;       obase = 0; }
            else if (tw < 80)  { W = W2; K = 512; local = tw - 16;  obase = 65536; }
            else if (tw < 144) { W = W3; K = 512; local = tw - 80;  obase = 327680; }
            else               { W = W4; K = 512; local = tw - 144; obase = 589824; }
            int nkt = K >> 6;
            int h = local / nkt, kt = local - h * nkt;
            int k0 = kt * 64;
            for (int idx = tid; idx < 4096; idx += 256) {
                int r = idx >> 6, c = idx & 63;
                tt[r][c] = W[(size_t)h * K * FO + (size_t)(k0 + r) * FO + c];
            }
            __syncthreads();
            for (int idx = tid; idx < 4096; idx += 256) {
                int o = idx >> 6, kk = idx & 63;
                float v = tt[kk][o];
                unsigned short hb = f2bf(v);
                size_t dst = obase + (size_t)(h * FO + o) * K + k0 + kk;
                Wth[dst] = hb;
                Wtl[dst] = f2bf(v - bf2f(hb));
            }
            __syncthreads();
        } else {
            int row = (t - 464) * 4 + ws;
            const float* arow = adj + (size_t)row * NN;
            int count = 0;
            for (int base = 0; base < NN; base += 64) {
                float v = arow[base + lane];
                unsigned long long m = __ballot(v > 0.0f);
                if (v > 0.0f) {
                    int pos = count + __popcll(m & ((1ull << lane) - 1ull));
                    if (pos < MAXDEG) nbr[(size_t)row * MAXDEG + pos] = base + lane;
                }
                count += __popcll(m);
            }
            if (lane == 0) deg[row] = count < MAXDEG ? count : MAXDEG;
        }
    }
    gridbar(bar, ++ph * (unsigned)NBLK);

    // ================= layer loop =================
    const float* aps[4] = {a1, a2, a3, a4};
    const size_t woff[4] = {0, 65536, 327680, 589824};
    int K = 128;

    for (int L = 0; L < 4; ++L) {
        const unsigned short* Bh = Wth + woff[L];
        const unsigned short* Bl = Wtl + woff[L];
        const float* av_g = aps[L];

        // ---- GEMM + ee phase: 384 tasks ----
        for (int t = b; t < 384; t += NBLK) {
            const int h = t & 7;
            const int r0 = (t >> 3) * 64;
            typedef float CsT[68];
            unsigned short* As_ = (unsigned short*)smem;
            unsigned short* Bs_ = (unsigned short*)(smem + 20480);
            CsT* Cs = reinterpret_cast<CsT*>(smem);

            const int wr = ws >> 1, wc = ws & 1;
            const int lr = lane & 15, lg = lane >> 4;

            const unsigned short* Bhh = Bh + (size_t)h * FO * K;
            const unsigned short* Bll = Bl + (size_t)h * FO * K;

            const int row0 = tid >> 3, cq0 = tid & 7;
            const int off0 = row0 * 80 + ((cq0 ^ (row0 & 7)) * 8);
            const size_t gA0 = (size_t)(r0 + row0) * K + cq0 * 8;
            const size_t gA1 = gA0 + (size_t)32 * K;
            const size_t gB0 = (size_t)row0 * K + cq0 * 8;
            const size_t gB1 = gB0 + (size_t)32 * K;

            bf16x8 ra0h, ra0l, ra1h, ra1l, rb0h, rb0l, rb1h, rb1l;

            auto loadg = [&](int k0) {
                ra0h = *(const bf16x8*)(Ah + gA0 + k0);
                ra0l = *(const bf16x8*)(Al + gA0 + k0);
                ra1h = *(const bf16x8*)(Ah + gA1 + k0);
                ra1l = *(const bf16x8*)(Al + gA1 + k0);
                rb0h = *(const bf16x8*)(Bhh + gB0 + k0);
                rb0l = *(const bf16x8*)(Bll + gB0 + k0);
                rb1h = *(const bf16x8*)(Bhh + gB1 + k0);
                rb1l = *(const bf16x8*)(Bll + gB1 + k0);
            };
            auto store_lds = [&]() {
                *(bf16x8*)&As_[off0] = ra0h;
                *(bf16x8*)&As_[off0 + 2560] = ra1h;
                *(bf16x8*)&As_[5120 + off0] = ra0l;
                *(bf16x8*)&As_[5120 + off0 + 2560] = ra1l;
                *(bf16x8*)&Bs_[off0] = rb0h;
                *(bf16x8*)&Bs_[off0 + 2560] = rb1h;
                *(bf16x8*)&Bs_[5120 + off0] = rb0l;
                *(bf16x8*)&Bs_[5120 + off0 + 2560] = rb1l;
            };

            f32x4 acc[2][2];
            #pragma unroll
            for (int i = 0; i < 2; ++i)
                #pragma unroll
                for (int j = 0; j < 2; ++j) acc[i][j] = (f32x4){0.f, 0.f, 0.f, 0.f};

            auto mfma_phase = [&]() {
                #pragma unroll
                for (int ks = 0; ks < 2; ++ks) {
                    bf16x8 ah[2], al[2], bh[2], bl[2];
                    int cq = ks * 4 + lg;
                    #pragma unroll
                    for (int i = 0; i < 2; ++i) {
                        int row = wr * 32 + i * 16 + lr;
                        int offa = row * 80 + ((cq ^ (row & 7)) * 8);
                        ah[i] = *(const bf16x8*)&As_[offa];
                        al[i] = *(const bf16x8*)&As_[5120 + offa];
                        int col = wc * 32 + i * 16 + lr;
                        int offb = col * 80 + ((cq ^ (col & 7)) * 8);
                        bh[i] = *(const bf16x8*)&Bs_[offb];
                        bl[i] = *(const bf16x8*)&Bs_[5120 + offb];
                    }
                    #pragma unroll
                    for (int i = 0; i < 2; ++i)
                        #pragma unroll
                        for (int j = 0; j < 2; ++j) {
                            acc[i][j] = __builtin_amdgcn_mfma_f32_16x16x32_bf16(ah[i], bh[j], acc[i][j], 0, 0, 0);
                            acc[i][j] = __builtin_amdgcn_mfma_f32_16x16x32_bf16(ah[i], bl[j], acc[i][j], 0, 0, 0);
                            acc[i][j] = __builtin_amdgcn_mfma_f32_16x16x32_bf16(al[i], bh[j], acc[i][j], 0, 0, 0);
                        }
                }
            };

            loadg(0);
            store_lds();
            __syncthreads();
            for (int k0 = 64; k0 < K; k0 += 64) {
                loadg(k0);
                mfma_phase();
                __syncthreads();
                store_lds();
                __syncthreads();
            }
            mfma_phase();
            __syncthreads();

            #pragma unroll
            for (int i = 0; i < 2; ++i)
                #pragma unroll
                for (int j = 0; j < 2; ++j)
                    #pragma unroll
                    for (int r = 0; r < 4; ++r)
                        Cs[wr * 32 + i * 16 + lg * 4 + r][wc * 32 + j * 16 + lr] = acc[i][j][r];
            __syncthreads();

            #pragma unroll
            for (int it = 0; it < 4; ++it) {
                int idx = tid + it * 256;
                int r = idx >> 4, c4 = idx & 15;
                *(float4*)&WhF[(size_t)(r0 + r) * FCAT + h * FO + c4 * 4] = *(float4*)&Cs[r][c4 * 4];
            }

            {
                int r = tid >> 2, sub = tid & 3;
                const float* av = av_g + h * 2 * FO;
                float s = 0.0f, dd = 0.0f;
                #pragma unroll
                for (int k = 0; k < 16; ++k) {
                    float v = Cs[r][sub * 16 + k];
                    s = fmaf(v, av[sub * 16 + k], s);
                    dd = fmaf(v, av[FO + sub * 16 + k], dd);
                }
                s += __shfl_xor(s, 1); s += __shfl_xor(s, 2);
                dd += __shfl_xor(dd, 1); dd += __shfl_xor(dd, 2);
                if (sub == 0) {
                    esrc[h * NN + r0 + r] = s;
                    edst[h * NN + r0 + r] = dd;
                }
            }
            __syncthreads();
        }
        gridbar(bar, ++ph * (unsigned)NBLK);

        // ---- attention + aggregation phase: per-wave tasks, h-major ----
        {
            float (*pbuf)[MAXDEG] = (float(*)[MAXDEG])smem;
            int (*jbuf)[MAXDEG] = (int(*)[MAXDEG])(smem + 4 * MAXDEG * sizeof(float));
            const int write_f32 = (L == 3);
            for (int wt = b * 4 + ws; wt < NH * NN; wt += NBLK * 4) {
                const int h = wt / NN;
                const int n = wt - h * NN;
                const int d = deg[n];
                const int* nb = nbr + (size_t)n * MAXDEG;
                const float es = esrc[h * NN + n];
                const float* ed = edst + h * NN;

                for (int tt = lane; tt < d; tt += 64) {
                    int j = nb[tt];
                    float e = es + ed[j];
                    e = (e > 0.0f) ? e : ALPHA * e;
                    jbuf[ws][tt] = j;
                    pbuf[ws][tt] = e;
                }
                float lm = -3.0e38f;
                for (int tt = lane; tt < d; tt += 64) lm = fmaxf(lm, pbuf[ws][tt]);
                #pragma unroll
                for (int off = 32; off; off >>= 1) lm = fmaxf(lm, __shfl_xor(lm, off));
                float lsum = 0.0f;
                for (int tt = lane; tt < d; tt += 64) {
                    float pv = __expf(pbuf[ws][tt] - lm);
                    pbuf[ws][tt] = pv;
                    lsum += pv;
                }
                #pragma unroll
                for (int off = 32; off; off >>= 1) lsum += __shfl_xor(lsum, off);

                const float* whb = WhF + h * FO + lane;
                float q0 = 0.f, q1 = 0.f, q2 = 0.f, q3 = 0.f;
                int tt = 0;
                for (; tt + 3 < d; tt += 4) {
                    q0 = fmaf(pbuf[ws][tt + 0], whb[(size_t)jbuf[ws][tt + 0] * FCAT], q0);
                    q1 = fmaf(pbuf[ws][tt + 1], whb[(size_t)jbuf[ws][tt + 1] * FCAT], q1);
                    q2 = fmaf(pbuf[ws][tt + 2], whb[(size_t)jbuf[ws][tt + 2] * FCAT], q2);
                    q3 = fmaf(pbuf[ws][tt + 3], whb[(size_t)jbuf[ws][tt + 3] * FCAT], q3);
                }
                for (; tt < d; ++tt)
                    q0 = fmaf(pbuf[ws][tt], whb[(size_t)jbuf[ws][tt] * FCAT], q0);
                float acc = (q0 + q1) + (q2 + q3);
                acc /= lsum;
                float r = (acc > 0.0f) ? acc : (__expf(acc) - 1.0f);  // ELU
                size_t idx = (size_t)n * FCAT + h * FO + lane;
                if (write_f32) {
                    out[idx] = r;
                } else {
                    unsigned short hb = f2bf(r);
                    Ah[idx] = hb;
                    Al[idx] = f2bf(r - bf2f(hb));
                }
            }
        }
        if (L < 3) gridbar(bar, ++ph * (unsigned)NBLK);
        K = FCAT;
    }
}

extern "C" void kernel_launch(void* const* d_in, const int* in_sizes, int n_in,
                              void* d_out, int out_size, void* d_ws, size_t ws_size,
                              hipStream_t stream) {
    const float* x   = (const float*)d_in[0];
    const float* adj = (const float*)d_in[1];
    const float* W1 = (const float*)d_in[2];
    const float* a1 = (const float*)d_in[3];
    const float* W2 = (const float*)d_in[4];
    const float* a2 = (const float*)d_in[5];
    const float* W3 = (const float*)d_in[6];
    const float* a3 = (const float*)d_in[7];
    const float* W4 = (const float*)d_in[8];
    const float* a4 = (const float*)d_in[9];
    float* out = (float*)d_out;

    char* p = (char*)d_ws;
    unsigned* bar = (unsigned*)p;    p += 256;
    int* deg = (int*)p;              p += (size_t)NN * sizeof(int);
    int* nbr = (int*)p;              p += (size_t)NN * MAXDEG * sizeof(int);
    unsigned short* Ah = (unsigned short*)p; p += (size_t)NN * FCAT * 2;
    unsigned short* Al = (unsigned short*)p; p += (size_t)NN * FCAT * 2;
    float* WhF = (float*)p;          p += (size_t)NN * FCAT * sizeof(float);
    unsigned short* Wth = (unsigned short*)p; p += (size_t)851968 * 2;
    unsigned short* Wtl = (unsigned short*)p; p += (size_t)851968 * 2;
    float* esrc = (float*)p;         p += (size_t)NN * NH * sizeof(float);
    float* edst = (float*)p;         p += (size_t)NN * NH * sizeof(float);

    hipMemsetAsync(bar, 0, sizeof(unsigned), stream);

    gat_all_k<<<NBLK, 256, 0, stream>>>(x, adj, W1, W2, W3, W4, a1, a2, a3, a4,
                                        Ah, Al, Wth, Wtl, deg, nbr, WhF, esrc, edst,
                                        out, bar);
}

// Round 12
// 140.904 us; speedup vs baseline: 5.2929x; 5.2929x over previous
//
#include <hip/hip_runtime.h>
#include <math.h>

#define NN 3072
#define NH 8
#define FO 64
#define FCAT 512
#define MAXDEG 128
#define ALPHA 0.2f

typedef __attribute__((ext_vector_type(8))) short bf16x8;
typedef __attribute__((ext_vector_type(4))) float f32x4;

static __device__ __forceinline__ unsigned short f2bf(float v) {
    union { float f; unsigned u; } x; x.f = v;
    unsigned r = x.u + 0x7fffu + ((x.u >> 16) & 1u);
    return (unsigned short)(r >> 16);
}
static __device__ __forceinline__ float bf2f(unsigned short b) {
    union { unsigned u; float f; } x; x.u = ((unsigned)b) << 16;
    return x.f;
}

// ---------------- fused prelude: conv_x + conv_wt + csr (R7 verbatim) ----------------
__global__ __launch_bounds__(256) void prelude_k(const float* __restrict__ x,
                                                 const float* __restrict__ adj,
                                                 const float* __restrict__ W1,
                                                 const float* __restrict__ W2,
                                                 const float* __restrict__ W3,
                                                 const float* __restrict__ W4,
                                                 unsigned short* __restrict__ Ah,
                                                 unsigned short* __restrict__ Al,
                                                 unsigned short* __restrict__ Wth,
                                                 unsigned short* __restrict__ Wtl,
                                                 int* __restrict__ deg,
                                                 int* __restrict__ nbr) {
    __shared__ float t[64][65];
    const int b = blockIdx.x, tid = threadIdx.x;

    if (b < 256) {
        int base = b * 1536 + tid;
        #pragma unroll
        for (int i = 0; i < 6; ++i) {
            int idx = base + i * 256;
            float v = x[idx];
            unsigned short hb = f2bf(v);
            Ah[idx] = hb;
            Al[idx] = f2bf(v - bf2f(hb));
        }
        if (b < 208) {
            const float* W; int K; int local; size_t obase;
            if (b < 16)       { W = W1; K = 128; local = b;       obase = 0; }
            else if (b < 80)  { W = W2; K = 512; local = b - 16;  obase = 65536; }
            else if (b < 144) { W = W3; K = 512; local = b - 80;  obase = 327680; }
            else              { W = W4; K = 512; local = b - 144; obase = 589824; }
            int nkt = K >> 6;
            int h = local / nkt, kt = local - h * nkt;
            int k0 = kt * 64;
            for (int idx = tid; idx < 4096; idx += 256) {
                int r = idx >> 6, c = idx & 63;
                t[r][c] = W[(size_t)h * K * FO + (size_t)(k0 + r) * FO + c];
            }
            __syncthreads();
            for (int idx = tid; idx < 4096; idx += 256) {
                int o = idx >> 6, kk = idx & 63;
                float v = t[kk][o];
                unsigned short hb = f2bf(v);
                size_t dst = obase + (size_t)(h * FO + o) * K + k0 + kk;
                Wth[dst] = hb;
                Wtl[dst] = f2bf(v - bf2f(hb));
            }
        }
    } else {
        int row = (b - 256) * 4 + (tid >> 6);
        int lane = tid & 63;
        const float* arow = adj + (size_t)row * NN;
        int count = 0;
        for (int base = 0; base < NN; base += 64) {
            float v = arow[base + lane];
            unsigned long long m = __ballot(v > 0.0f);
            if (v > 0.0f) {
                int pos = count + __popcll(m & ((1ull << lane) - 1ull));
                if (pos < MAXDEG) nbr[(size_t)row * MAXDEG + pos] = base + lane;
            }
            count += __popcll(m);
        }
        if (lane == 0) deg[row] = count < MAXDEG ? count : MAXDEG;
    }
}

// ---------------- split-bf16 MFMA GEMM: 32x64 tile, VGPR prefetch, 768 blocks (3/CU) --------
// grid (NH, NN/32); block 256 = 4 waves (2 wr x 2 wc), each wave 16x32 of the tile.
__global__ __launch_bounds__(256, 3) void gemm_ee_k(const unsigned short* __restrict__ Ah,
                                                    const unsigned short* __restrict__ Al,
                                                    const unsigned short* __restrict__ Bh,
                                                    const unsigned short* __restrict__ Bl,
                                                    const float* __restrict__ a,
                                                    float* __restrict__ C,
                                                    float* __restrict__ esrc,
                                                    float* __restrict__ edst, int K) {
    __shared__ __align__(16) unsigned char smem[30720];
    typedef float CsT[68];
    unsigned short* As_ = (unsigned short*)smem;            // As[2][32][80] hi/lo (10240 B)
    unsigned short* Bs_ = (unsigned short*)(smem + 10240);  // Bs[2][64][80] (20480 B)
    CsT* Cs = reinterpret_cast<CsT*>(smem);                 // Cs[32][68] overlay (8704 B)

    const int tid = threadIdx.x;
    const int h = blockIdx.x;
    const int r0 = blockIdx.y * 32;
    const int lane = tid & 63;
    const int wid = tid >> 6;
    const int wr = wid >> 1, wc = wid & 1;
    const int lr = lane & 15, lg = lane >> 4;

    const unsigned short* Bhh = Bh + (size_t)h * FO * K;
    const unsigned short* Bll = Bl + (size_t)h * FO * K;

    // staging: thread covers A slot (row0, cq0) and B slots (row0, cq0), (row0+32, cq0)
    const int row0 = tid >> 3, cq0 = tid & 7;
    const int off0 = row0 * 80 + ((cq0 ^ (row0 & 7)) * 8);   // (row+32)&7 == row&7 -> +2560
    const size_t gA0 = (size_t)(r0 + row0) * K + cq0 * 8;
    const size_t gB0 = (size_t)row0 * K + cq0 * 8;
    const size_t gB1 = gB0 + (size_t)32 * K;

    bf16x8 rah, ral, rb0h, rb0l, rb1h, rb1l;

    auto loadg = [&](int k0) {
        rah = *(const bf16x8*)(Ah + gA0 + k0);
        ral = *(const bf16x8*)(Al + gA0 + k0);
        rb0h = *(const bf16x8*)(Bhh + gB0 + k0);
        rb0l = *(const bf16x8*)(Bll + gB0 + k0);
        rb1h = *(const bf16x8*)(Bhh + gB1 + k0);
        rb1l = *(const bf16x8*)(Bll + gB1 + k0);
    };
    auto store_lds = [&]() {
        *(bf16x8*)&As_[off0] = rah;
        *(bf16x8*)&As_[2560 + off0] = ral;
        *(bf16x8*)&Bs_[off0] = rb0h;
        *(bf16x8*)&Bs_[5120 + off0] = rb0l;
        *(bf16x8*)&Bs_[off0 + 2560] = rb1h;
        *(bf16x8*)&Bs_[5120 + off0 + 2560] = rb1l;
    };

    f32x4 acc[2];
    acc[0] = (f32x4){0.f, 0.f, 0.f, 0.f};
    acc[1] = (f32x4){0.f, 0.f, 0.f, 0.f};

    auto mfma_phase = [&]() {
        #pragma unroll
        for (int ks = 0; ks < 2; ++ks) {
            int cq = ks * 4 + lg;
            int arow = wr * 16 + lr;
            int offa = arow * 80 + ((cq ^ (arow & 7)) * 8);
            bf16x8 ah = *(const bf16x8*)&As_[offa];
            bf16x8 al = *(const bf16x8*)&As_[2560 + offa];
            bf16x8 bh[2], bl[2];
            #pragma unroll
            for (int j = 0; j < 2; ++j) {
                int col = wc * 32 + j * 16 + lr;
                int offb = col * 80 + ((cq ^ (col & 7)) * 8);
                bh[j] = *(const bf16x8*)&Bs_[offb];
                bl[j] = *(const bf16x8*)&Bs_[5120 + offb];
            }
            #pragma unroll
            for (int j = 0; j < 2; ++j) {
                acc[j] = __builtin_amdgcn_mfma_f32_16x16x32_bf16(ah, bh[j], acc[j], 0, 0, 0);
                acc[j] = __builtin_amdgcn_mfma_f32_16x16x32_bf16(ah, bl[j], acc[j], 0, 0, 0);
                acc[j] = __builtin_amdgcn_mfma_f32_16x16x32_bf16(al, bh[j], acc[j], 0, 0, 0);
            }
        }
    };

    // prologue: stage tile 0
    loadg(0);
    store_lds();
    __syncthreads();
    // main loop: prefetch tile k0 into VGPRs while MFMA-ing previous tile
    for (int k0 = 64; k0 < K; k0 += 64) {
        loadg(k0);
        mfma_phase();
        __syncthreads();
        store_lds();
        __syncthreads();
    }
    mfma_phase();
    __syncthreads();

    // stage C tile (32x64 fp32) in LDS (overlays As region only)
    #pragma unroll
    for (int j = 0; j < 2; ++j)
        #pragma unroll
        for (int r = 0; r < 4; ++r)
            Cs[wr * 16 + lg * 4 + r][wc * 32 + j * 16 + lr] = acc[j][r];
    __syncthreads();

    // coalesced float4 C stores (512 float4 over 256 threads)
    #pragma unroll
    for (int it = 0; it < 2; ++it) {
        int idx = tid + it * 256;
        int r = idx >> 4, c4 = idx & 15;
        *(float4*)&C[(size_t)(r0 + r) * FCAT + h * FO + c4 * 4] = *(float4*)&Cs[r][c4 * 4];
    }

    // fused e_src/e_dst: 8 lanes per row x 8 elems, 3-step shuffle reduce
    {
        int r = tid >> 3, sub = tid & 7;
        const float* av = a + h * 2 * FO;
        float s = 0.0f, dd = 0.0f;
        #pragma unroll
        for (int k = 0; k < 8; ++k) {
            float v = Cs[r][sub * 8 + k];
            s = fmaf(v, av[sub * 8 + k], s);
            dd = fmaf(v, av[FO + sub * 8 + k], dd);
        }
        s += __shfl_xor(s, 1); s += __shfl_xor(s, 2); s += __shfl_xor(s, 4);
        dd += __shfl_xor(dd, 1); dd += __shfl_xor(dd, 2); dd += __shfl_xor(dd, 4);
        if (sub == 0) {
            esrc[h * NN + r0 + r] = s;
            edst[h * NN + r0 + r] = dd;
        }
    }
}

// ---------------- attention + aggregation: h-major block order (R7 verbatim) ---------------
__global__ __launch_bounds__(256) void attn_agg_k(const float* __restrict__ Wh,
                                                  const float* __restrict__ esrc,
                                                  const float* __restrict__ edst,
                                                  const int* __restrict__ deg,
                                                  const int* __restrict__ nbr,
                                                  float* __restrict__ outp,
                                                  unsigned short* __restrict__ oh,
                                                  unsigned short* __restrict__ ol,
                                                  int write_f32) {
    __shared__ float pbuf[4][MAXDEG];
    __shared__ int jbuf[4][MAXDEG];
    const int ws = threadIdx.x >> 6;
    const int lane = threadIdx.x & 63;
    const int h = blockIdx.x / (NN / 4);
    const int n = (blockIdx.x % (NN / 4)) * 4 + ws;
    const int d = deg[n];
    const int* nb = nbr + (size_t)n * MAXDEG;
    const float es = esrc[h * NN + n];
    const float* ed = edst + h * NN;

    for (int t = lane; t < d; t += 64) {
        int j = nb[t];
        float e = es + ed[j];
        e = (e > 0.0f) ? e : ALPHA * e;
        jbuf[ws][t] = j;
        pbuf[ws][t] = e;
    }
    float lm = -3.0e38f;
    for (int t = lane; t < d; t += 64) lm = fmaxf(lm, pbuf[ws][t]);
    #pragma unroll
    for (int off = 32; off; off >>= 1) lm = fmaxf(lm, __shfl_xor(lm, off));
    float lsum = 0.0f;
    for (int t = lane; t < d; t += 64) {
        float pv = __expf(pbuf[ws][t] - lm);
        pbuf[ws][t] = pv;
        lsum += pv;
    }
    #pragma unroll
    for (int off = 32; off; off >>= 1) lsum += __shfl_xor(lsum, off);

    const float* whb = Wh + h * FO + lane;
    float a0 = 0.f, a1 = 0.f, a2 = 0.f, a3 = 0.f;
    int t = 0;
    for (; t + 3 < d; t += 4) {
        a0 = fmaf(pbuf[ws][t + 0], whb[(size_t)jbuf[ws][t + 0] * FCAT], a0);
        a1 = fmaf(pbuf[ws][t + 1], whb[(size_t)jbuf[ws][t + 1] * FCAT], a1);
        a2 = fmaf(pbuf[ws][t + 2], whb[(size_t)jbuf[ws][t + 2] * FCAT], a2);
        a3 = fmaf(pbuf[ws][t + 3], whb[(size_t)jbuf[ws][t + 3] * FCAT], a3);
    }
    for (; t < d; ++t)
        a0 = fmaf(pbuf[ws][t], whb[(size_t)jbuf[ws][t] * FCAT], a0);
    float acc = (a0 + a1) + (a2 + a3);
    acc /= lsum;
    float r = (acc > 0.0f) ? acc : (__expf(acc) - 1.0f);  // ELU
    size_t idx = (size_t)n * FCAT + h * FO + lane;
    if (write_f32) {
        outp[idx] = r;
    } else {
        unsigned short hb = f2bf(r);
        oh[idx] = hb;
        ol[idx] = f2bf(r - bf2f(hb));
    }
}

extern "C" void kernel_launch(void* const* d_in, const int* in_sizes, int n_in,
                              void* d_out, int out_size, void* d_ws, size_t ws_size,
                              hipStream_t stream) {
    const float* x   = (const float*)d_in[0];
    const float* adj = (const float*)d_in[1];
    const float* ap[4] = {(const float*)d_in[3], (const float*)d_in[5],
                          (const float*)d_in[7], (const float*)d_in[9]};
    float* out = (float*)d_out;

    char* p = (char*)d_ws;
    int* deg = (int*)p;              p += (size_t)NN * sizeof(int);
    int* nbr = (int*)p;              p += (size_t)NN * MAXDEG * sizeof(int);
    unsigned short* Ah = (unsigned short*)p; p += (size_t)NN * FCAT * 2;
    unsigned short* Al = (unsigned short*)p; p += (size_t)NN * FCAT * 2;
    float* WhF = (float*)p;          p += (size_t)NN * FCAT * sizeof(float);
    unsigned short* Wth = (unsigned short*)p; p += (size_t)851968 * 2;
    unsigned short* Wtl = (unsigned short*)p; p += (size_t)851968 * 2;
    float* esrc = (float*)p;         p += (size_t)NN * NH * sizeof(float);
    float* edst = (float*)p;         p += (size_t)NN * NH * sizeof(float);

    prelude_k<<<1024, 256, 0, stream>>>(x, adj,
                                        (const float*)d_in[2], (const float*)d_in[4],
                                        (const float*)d_in[6], (const float*)d_in[8],
                                        Ah, Al, Wth, Wtl, deg, nbr);

    const size_t woff[4] = {0, 65536, 327680, 589824};
    int K = 128;
    for (int L = 0; L < 4; ++L) {
        dim3 g(NH, NN / 32);
        gemm_ee_k<<<g, 256, 0, stream>>>(Ah, Al, Wth + woff[L], Wtl + woff[L],
                                         ap[L], WhF, esrc, edst, K);
        attn_agg_k<<<NH * (NN / 4), 256, 0, stream>>>(WhF, esrc, edst, deg, nbr,
                                                      out, Ah, Al, L == 3 ? 1 : 0);
        K = FCAT;
    }
}